// Round 12
// baseline (125.540 us; speedup 1.0000x reference)
//
#include <hip/hip_runtime.h>
#include <math.h>

#define HW_ (1024*1024)

__device__ __forceinline__ float wave_red(float a) {
    a += __shfl_xor(a, 1);  a += __shfl_xor(a, 2);  a += __shfl_xor(a, 4);
    a += __shfl_xor(a, 8);  a += __shfl_xor(a, 16); a += __shfl_xor(a, 32);
    return a;
}

// ============ fully-fused splat stack: lr -> s0 -> s1 -> s2 -> s3 (ws3) ============
// grid (256, B): each block owns ONE s3 output pixel (ty,tx), all 64 channels.
__global__ void k_splat(const float* __restrict__ lr,
                        const float* __restrict__ sw0, const float* __restrict__ sb0,
                        const float* __restrict__ sw1, const float* __restrict__ sb1,
                        const float* __restrict__ sw2, const float* __restrict__ sb2,
                        const float* __restrict__ sw3, const float* __restrict__ sb3,
                        float* __restrict__ ws3)
{
    __shared__ float lrs[3 * 31 * 32];   // 2976
    __shared__ float s0b[8 * 15 * 16];   // 1920
    __shared__ float s1b[16 * 7 * 8];    // 896
    __shared__ float s2b[32 * 9];        // 288
    __shared__ float w1s[1152];
    __shared__ float w2s[4608];
    int b = blockIdx.y;
    int ty = blockIdx.x >> 4, tx = blockIdx.x & 15;
    int t = threadIdx.x;

    for (int i = t; i < 2883; i += 256) {
        int c = i / 961, rem = i % 961, y = rem / 31, x = rem % 31;
        int gy = 16 * ty - 15 + y, gx = 16 * tx - 15 + x;
        float val = 0.f;
        if ((unsigned)gy < 256u && (unsigned)gx < 256u)
            val = lr[(((size_t)b * 3 + c) << 16) + (gy << 8) + gx];
        lrs[c * 992 + y * 32 + x] = val;
    }
    for (int i = t; i < 1152; i += 256) w1s[i] = sw1[i];
    for (int i = t; i < 4608; i += 256) w2s[i] = sw2[i];
    __syncthreads();

    for (int i = t; i < 1800; i += 256) {
        int c = i / 225, rem = i % 225, y = rem / 15, x = rem % 15;
        int gy = 8 * ty - 7 + y, gx = 8 * tx - 7 + x;
        float val = 0.f;
        if ((unsigned)gy < 128u && (unsigned)gx < 128u) {
            float acc = sb0[c];
            const float* wp = sw0 + c * 27;
            #pragma unroll
            for (int ci = 0; ci < 3; ci++) {
                const float* sp = lrs + ci * 992;
                #pragma unroll
                for (int kh = 0; kh < 3; kh++)
                    #pragma unroll
                    for (int kw = 0; kw < 3; kw++)
                        acc = fmaf(sp[(2 * y + kh) * 32 + 2 * x + kw],
                                   wp[ci * 9 + kh * 3 + kw], acc);
            }
            val = fmaxf(acc, 0.f);
        }
        s0b[c * 240 + y * 16 + x] = val;
    }
    __syncthreads();

    for (int i = t; i < 784; i += 256) {
        int c = i / 49, rem = i % 49, y = rem / 7, x = rem % 7;
        int gy = 4 * ty - 3 + y, gx = 4 * tx - 3 + x;
        float val = 0.f;
        if ((unsigned)gy < 64u && (unsigned)gx < 64u) {
            float acc = sb1[c];
            const float* wp = w1s + c * 72;
            #pragma unroll
            for (int ci = 0; ci < 8; ci++) {
                const float* sp = s0b + ci * 240;
                #pragma unroll
                for (int kh = 0; kh < 3; kh++)
                    #pragma unroll
                    for (int kw = 0; kw < 3; kw++)
                        acc = fmaf(sp[(2 * y + kh) * 16 + 2 * x + kw],
                                   wp[ci * 9 + kh * 3 + kw], acc);
            }
            val = fmaxf(acc, 0.f);
        }
        s1b[c * 56 + y * 8 + x] = val;
    }
    __syncthreads();

    for (int i = t; i < 288; i += 256) {
        int c = i / 9, rem = i % 9, y = rem / 3, x = rem % 3;
        int gy = 2 * ty - 1 + y, gx = 2 * tx - 1 + x;
        float val = 0.f;
        if ((unsigned)gy < 32u && (unsigned)gx < 32u) {
            float acc = sb2[c];
            const float* wp = w2s + c * 144;
            #pragma unroll
            for (int ci = 0; ci < 16; ci++) {
                const float* sp = s1b + ci * 56;
                #pragma unroll
                for (int kh = 0; kh < 3; kh++)
                    #pragma unroll
                    for (int kw = 0; kw < 3; kw++)
                        acc = fmaf(sp[(2 * y + kh) * 8 + 2 * x + kw],
                                   wp[ci * 9 + kh * 3 + kw], acc);
            }
            val = fmaxf(acc, 0.f);
        }
        s2b[c * 9 + y * 3 + x] = val;
    }
    __syncthreads();

    {
        int c = t >> 2, sub = t & 3;
        float acc = 0.f;
        const float* wp = sw3 + c * 288 + sub * 72;
        #pragma unroll
        for (int ci8 = 0; ci8 < 8; ci8++) {
            const float* sp = s2b + (sub * 8 + ci8) * 9;
            #pragma unroll
            for (int k = 0; k < 9; k++)
                acc = fmaf(sp[k], wp[ci8 * 9 + k], acc);
        }
        acc += __shfl_xor(acc, 1);
        acc += __shfl_xor(acc, 2);
        if (sub == 0)
            ws3[(((size_t)b * 64 + c) * 16 + ty) * 16 + tx] = fmaxf(acc + sb3[c], 0.f);
    }
}

// ---- lw0 || gcw0, full input map in LDS ([64][16][18]); weights via LDS; 4-acc ILP ----
// grid (80, B)
__global__ void k_loc0_gc0(const float* __restrict__ ws3,
                           const float* __restrict__ lw0, const float* __restrict__ lb0,
                           float* __restrict__ loc0,
                           const float* __restrict__ gcw0, const float* __restrict__ gcb0,
                           float* __restrict__ g0)
{
    __shared__ float smem[20736];        // inp 18432 + weights 2304
    float* inp = smem;
    float* wgt = smem + 18432;
    int b = blockIdx.y, t = threadIdx.x;

    for (int i = t; i < 2048; i += 256) {
        int ci = i >> 5, rem = i & 31;
        inp[ci * 288 + (rem >> 1) * 18 + (rem & 1) * 17] = 0.f;
    }
    {
        const float4* src = (const float4*)(ws3 + ((size_t)b << 14));
        #pragma unroll
        for (int k = 0; k < 16; k++) {
            int i = t + (k << 8);
            float4 vv = src[i];
            int flat = i << 2;
            float* d = inp + (flat >> 8) * 288 + ((flat >> 4) & 15) * 18 + (flat & 15) + 1;
            d[0] = vv.x; d[1] = vv.y; d[2] = vv.z; d[3] = vv.w;
        }
    }
    if (blockIdx.x < 64) {
        int co = blockIdx.x;
        if (t < 144) ((float4*)wgt)[t] = ((const float4*)(lw0 + co * 576))[t];
        __syncthreads();
        int ho = t >> 4, wo = t & 15;
        float a0 = 0.f, a1 = 0.f, a2 = 0.f, a3 = 0.f;
        for (int ci = 0; ci < 16; ci++) {
            #pragma unroll
            for (int kh = 0; kh < 3; kh++) {
                int hi = ho - 1 + kh;
                if ((unsigned)hi >= 16u) continue;
                const float* qa = inp + ci * 288 + hi * 18 + wo;
                const float* wa = wgt + ci * 9 + kh * 3;
                a0 = fmaf(qa[0], wa[0], a0); a0 = fmaf(qa[1], wa[1], a0); a0 = fmaf(qa[2], wa[2], a0);
                const float* qb = qa + 16 * 288; const float* wb2 = wa + 144;
                a1 = fmaf(qb[0], wb2[0], a1); a1 = fmaf(qb[1], wb2[1], a1); a1 = fmaf(qb[2], wb2[2], a1);
                const float* qc = qa + 32 * 288; const float* wc = wa + 288;
                a2 = fmaf(qc[0], wc[0], a2); a2 = fmaf(qc[1], wc[1], a2); a2 = fmaf(qc[2], wc[2], a2);
                const float* qd = qa + 48 * 288; const float* wd = wa + 432;
                a3 = fmaf(qd[0], wd[0], a3); a3 = fmaf(qd[1], wd[1], a3); a3 = fmaf(qd[2], wd[2], a3);
            }
        }
        float acc = lb0[co] + ((a0 + a1) + (a2 + a3));
        loc0[((size_t)(b * 64 + co) << 8) + t] = fmaxf(acc, 0.f);
    } else {
        int cb = (blockIdx.x - 64) << 2;
        for (int i = t; i < 2304; i += 256) wgt[i] = gcw0[cb * 576 + i];
        __syncthreads();
        int sub = t >> 6, co = cb + sub;
        int px = t & 63, ho = px >> 3, wo = px & 7;
        const float* wb = wgt + sub * 576;
        float a0 = 0.f, a1 = 0.f, a2 = 0.f, a3 = 0.f;
        for (int ci = 0; ci < 16; ci++) {
            #pragma unroll
            for (int kh = 0; kh < 3; kh++) {
                int hi = (ho << 1) - 1 + kh;
                if ((unsigned)hi >= 16u) continue;
                const float* qa = inp + ci * 288 + hi * 18 + (wo << 1);
                const float* wa = wb + ci * 9 + kh * 3;
                a0 = fmaf(qa[0], wa[0], a0); a0 = fmaf(qa[1], wa[1], a0); a0 = fmaf(qa[2], wa[2], a0);
                const float* qb = qa + 16 * 288; const float* wb2 = wa + 144;
                a1 = fmaf(qb[0], wb2[0], a1); a1 = fmaf(qb[1], wb2[1], a1); a1 = fmaf(qb[2], wb2[2], a1);
                const float* qc = qa + 32 * 288; const float* wc = wa + 288;
                a2 = fmaf(qc[0], wc[0], a2); a2 = fmaf(qc[1], wc[1], a2); a2 = fmaf(qc[2], wc[2], a2);
                const float* qd = qa + 48 * 288; const float* wd = wa + 432;
                a3 = fmaf(qd[0], wd[0], a3); a3 = fmaf(qd[1], wd[1], a3); a3 = fmaf(qd[2], wd[2], a3);
            }
        }
        float acc = gcb0[co] + ((a0 + a1) + (a2 + a3));
        g0[((size_t)(b * 64 + co) << 6) + px] = fmaxf(acc, 0.f);
    }
}

// ---- lw1 (no relu) || [gc1 redundant + fc0] ; LDS weights; 4-acc ILP. grid (96, B) ----
// blocks 0-63: loc1. blocks 64-95: rebuild v in LDS (gc1 from g0, gcw1 streamed in
// 4 chunks) then compute 8 fc0 outputs. v/h0 chain shortened by one kernel.
__global__ void k_loc1_fc(const float* __restrict__ loc0,
                          const float* __restrict__ lw1, const float* __restrict__ lb1,
                          float* __restrict__ loc,
                          const float* __restrict__ g0,
                          const float* __restrict__ gcw1, const float* __restrict__ gcb1,
                          const float* __restrict__ fcw0, const float* __restrict__ fcb0,
                          float* __restrict__ h0)
{
    __shared__ float smem[19008];
    int b = blockIdx.y, t = threadIdx.x;
    if (blockIdx.x < 64) {
        float* inp = smem;               // [64][16][18]
        float* wloc = smem + 18432;      // 576
        int co = blockIdx.x;
        for (int i = t; i < 2048; i += 256) {
            int ci = i >> 5, rem = i & 31;
            inp[ci * 288 + (rem >> 1) * 18 + (rem & 1) * 17] = 0.f;
        }
        const float4* src = (const float4*)(loc0 + ((size_t)b << 14));
        #pragma unroll
        for (int k = 0; k < 16; k++) {
            int i = t + (k << 8);
            float4 vv = src[i];
            int flat = i << 2;
            float* d = inp + (flat >> 8) * 288 + ((flat >> 4) & 15) * 18 + (flat & 15) + 1;
            d[0] = vv.x; d[1] = vv.y; d[2] = vv.z; d[3] = vv.w;
        }
        if (t < 144) ((float4*)wloc)[t] = ((const float4*)(lw1 + co * 576))[t];
        __syncthreads();
        int ho = t >> 4, wo = t & 15;
        float a0 = 0.f, a1 = 0.f, a2 = 0.f, a3 = 0.f;
        for (int ci = 0; ci < 16; ci++) {
            #pragma unroll
            for (int kh = 0; kh < 3; kh++) {
                int hi = ho - 1 + kh;
                if ((unsigned)hi >= 16u) continue;
                const float* qa = inp + ci * 288 + hi * 18 + wo;
                const float* wa = wloc + ci * 9 + kh * 3;
                a0 = fmaf(qa[0], wa[0], a0); a0 = fmaf(qa[1], wa[1], a0); a0 = fmaf(qa[2], wa[2], a0);
                const float* qb = qa + 16 * 288; const float* wb2 = wa + 144;
                a1 = fmaf(qb[0], wb2[0], a1); a1 = fmaf(qb[1], wb2[1], a1); a1 = fmaf(qb[2], wb2[2], a1);
                const float* qc = qa + 32 * 288; const float* wc = wa + 288;
                a2 = fmaf(qc[0], wc[0], a2); a2 = fmaf(qc[1], wc[1], a2); a2 = fmaf(qc[2], wc[2], a2);
                const float* qd = qa + 48 * 288; const float* wd = wa + 432;
                a3 = fmaf(qd[0], wd[0], a3); a3 = fmaf(qd[1], wd[1], a3); a3 = fmaf(qd[2], wd[2], a3);
            }
        }
        loc[((size_t)(b * 64 + co) << 8) + t] = lb1[co] + ((a0 + a1) + (a2 + a3));  // no relu
    } else {
        float* inp = smem;               // [64][8][10] = 5120
        float* vls = smem + 5120;        // 1024
        float* wgt = smem + 6144;        // 9216
        int j = blockIdx.x - 64;         // 0..31
        for (int i = t; i < 1024; i += 256) {
            int ci = i >> 4, rem = i & 15;
            inp[ci * 80 + (rem >> 1) * 10 + (rem & 1) * 9] = 0.f;
        }
        const float4* src = (const float4*)(g0 + ((size_t)b << 12));
        #pragma unroll
        for (int k = 0; k < 4; k++) {
            int i = t + (k << 8);
            float4 vv = src[i];
            int flat = i << 2;
            float* d = inp + (flat >> 6) * 80 + ((flat >> 3) & 7) * 10 + (flat & 7) + 1;
            d[0] = vv.x; d[1] = vv.y; d[2] = vv.z; d[3] = vv.w;
        }
        // gc1 in 4 chunks of 16 co each -> v in LDS
        int sub = t >> 4, px = t & 15, ho = px >> 2, wo = px & 3;
        for (int cc = 0; cc < 4; cc++) {
            __syncthreads();             // inp staged (1st) / prev chunk compute done
            for (int i = t; i < 9216; i += 256) wgt[i] = gcw1[cc * 9216 + i];
            __syncthreads();
            int co = (cc << 4) + sub;
            const float* wb = wgt + sub * 576;
            float a0 = 0.f, a1 = 0.f, a2 = 0.f, a3 = 0.f;
            for (int ci = 0; ci < 16; ci++) {
                #pragma unroll
                for (int kh = 0; kh < 3; kh++) {
                    int hi = (ho << 1) - 1 + kh;
                    if ((unsigned)hi >= 8u) continue;
                    const float* qa = inp + ci * 80 + hi * 10 + (wo << 1);
                    const float* wa = wb + ci * 9 + kh * 3;
                    a0 = fmaf(qa[0], wa[0], a0); a0 = fmaf(qa[1], wa[1], a0); a0 = fmaf(qa[2], wa[2], a0);
                    const float* qb = qa + 16 * 80; const float* wb2 = wa + 144;
                    a1 = fmaf(qb[0], wb2[0], a1); a1 = fmaf(qb[1], wb2[1], a1); a1 = fmaf(qb[2], wb2[2], a1);
                    const float* qc = qa + 32 * 80; const float* wc = wa + 288;
                    a2 = fmaf(qc[0], wc[0], a2); a2 = fmaf(qc[1], wc[1], a2); a2 = fmaf(qc[2], wc[2], a2);
                    const float* qd = qa + 48 * 80; const float* wd = wa + 432;
                    a3 = fmaf(qd[0], wd[0], a3); a3 = fmaf(qd[1], wd[1], a3); a3 = fmaf(qd[2], wd[2], a3);
                }
            }
            vls[(co << 4) + px] = fmaxf(gcb1[co] + ((a0 + a1) + (a2 + a3)), 0.f);
        }
        __syncthreads();
        // fc0: 8 outputs per block (2 per wave), v from LDS
        int lane = t & 63, wv = t >> 6;
        #pragma unroll
        for (int k = 0; k < 2; k++) {
            int o = (j << 3) + (wv << 1) + k;
            const float4* wr = (const float4*)(fcw0 + o * 1024);
            float acc = 0.f;
            #pragma unroll
            for (int i = 0; i < 4; i++) {
                float4 aa = wr[i * 64 + lane];
                float4 xx = ((float4*)vls)[i * 64 + lane];
                acc += aa.x * xx.x + aa.y * xx.y + aa.z * xx.z + aa.w * xx.w;
            }
            acc = wave_red(acc);
            if (lane == 0) h0[b * 256 + o] = fmaxf(acc + fcb0[o], 0.f);
        }
    }
}

// ------- fc1 + fc2 (redundant, coalesced) + fusion + bg conv (bgw in LDS). grid (16,B) -------
__global__ void k_fc12bg(const float* __restrict__ h0,
                         const float* __restrict__ fcw1, const float* __restrict__ fcb1,
                         const float* __restrict__ fcw2, const float* __restrict__ fcb2,
                         const float* __restrict__ loc,
                         const float* __restrict__ bgw, const float* __restrict__ bgb,
                         float* __restrict__ grid_r)
{
    __shared__ float h0s[256];
    __shared__ float h1s[128];
    __shared__ float gvs[64];
    __shared__ float fus[1024];          // [64ch][16pix]
    __shared__ float bgws[96 * 65];      // pad-65 rows
    int b = blockIdx.y, r = blockIdx.x;
    int t = threadIdx.x, lane = t & 63, wv = t >> 6;

    h0s[t] = h0[b * 256 + t];
    for (int i4 = t; i4 < 1536; i4 += 256) {
        float4 vv = ((const float4*)bgw)[i4];
        int row = i4 >> 4, col = (i4 & 15) << 2;
        float* d = &bgws[row * 65 + col];
        d[0] = vv.x; d[1] = vv.y; d[2] = vv.z; d[3] = vv.w;
    }
    __syncthreads();
    {
        float4 x4 = ((float4*)h0s)[lane];
        #pragma unroll 2
        for (int i = 0; i < 32; i++) {
            int o = (wv << 5) + i;
            float4 a = ((const float4*)(fcw1 + o * 256))[lane];
            float acc = a.x * x4.x + a.y * x4.y + a.z * x4.z + a.w * x4.w;
            acc = wave_red(acc);
            if (lane == 0) h1s[o] = fmaxf(acc + fcb1[o], 0.f);
        }
    }
    __syncthreads();
    {
        float2 x2 = ((float2*)h1s)[lane];
        #pragma unroll 2
        for (int i = 0; i < 16; i++) {
            int o = (wv << 4) + i;
            float2 a = ((const float2*)(fcw2 + o * 128))[lane];
            float acc = a.x * x2.x + a.y * x2.y;
            acc = wave_red(acc);
            if (lane == 0) gvs[o] = acc + fcb2[o];
        }
    }
    __syncthreads();
    #pragma unroll
    for (int i = 0; i < 4; i++) {
        int idx = t + (i << 8);
        int c = idx >> 4, p = idx & 15;
        fus[idx] = fmaxf(loc[(((size_t)b * 64 + c) * 16 + r) * 16 + p] + gvs[c], 0.f);
    }
    __syncthreads();
    {
        int p = t & 15, cg = t >> 4;
        float acc6[6];
        #pragma unroll
        for (int j = 0; j < 6; j++) acc6[j] = bgb[cg + (j << 4)];
        #pragma unroll 8
        for (int k = 0; k < 64; k++) {
            float f = fus[k * 16 + p];
            #pragma unroll
            for (int j = 0; j < 6; j++)
                acc6[j] += bgws[(cg + (j << 4)) * 65 + k] * f;
        }
        #pragma unroll
        for (int j = 0; j < 6; j++) {
            int co = cg + (j << 4);
            int c12 = co >> 3, d = co & 7;
            grid_r[(((((size_t)b * 8 + d) * 16 + r) * 16 + p) * 12) + c12] = acc6[j];
        }
    }
}

// ------- fused guide + slice + apply: one image row per block, 4 px/thread -------
__global__ void guide_slice(const float* __restrict__ fr, const float* __restrict__ grid_r,
                            const float* __restrict__ guw0, const float* __restrict__ gub0,
                            const float* __restrict__ guw1, const float* __restrict__ gub1,
                            float* __restrict__ gd_out, float* __restrict__ fin_out)
{
    __shared__ float gy[8 * 196];        // z-stride 196 (4 mod 32): conflict-free z
    int y = blockIdx.x, b = blockIdx.y;
    int t = threadIdx.x;

    float ys = (y + 0.5f) * 0.015625f - 0.5f;
    float fy = floorf(ys);
    int y0 = min(max((int)fy, 0), 15), y1 = min(y0 + 1, 15);
    float wy = ys - fy;

    const float* gb = grid_r + (size_t)b * 24576;
    for (int i = t; i < 1536; i += 256) {
        int z = i / 192, rem = i - z * 192;
        float a = gb[z * 3072 + y0 * 192 + rem];
        float c = gb[z * 3072 + y1 * 192 + rem];
        gy[z * 196 + rem] = a + wy * (c - a);
    }
    __syncthreads();

    int rowoff = (y << 10) + (t << 2);
    const float* frb = fr + (size_t)b * 3 * HW_;
    float4 R4 = *(const float4*)(frb + rowoff);
    float4 G4 = *(const float4*)(frb + HW_ + rowoff);
    float4 B4 = *(const float4*)(frb + 2 * HW_ + rowoff);
    float rr[4] = {R4.x, R4.y, R4.z, R4.w};
    float gg[4] = {G4.x, G4.y, G4.z, G4.w};
    float bb[4] = {B4.x, B4.y, B4.z, B4.w};
    float gdv[4], O0[4], O1[4], O2[4];

    #pragma unroll
    for (int j = 0; j < 4; j++) {
        float r = rr[j], g = gg[j], bl = bb[j];
        float s = gub1[0];
        #pragma unroll
        for (int c = 0; c < 16; c++) {
            float h = fmaf(guw0[c * 3], r, fmaf(guw0[c * 3 + 1], g,
                      fmaf(guw0[c * 3 + 2], bl, gub0[c])));
            s = fmaf(guw1[c], fmaxf(h, 0.f), s);
        }
        float gd = 1.f / (1.f + __expf(-s));
        gdv[j] = gd;

        int x = (t << 2) + j;
        float xs = (x + 0.5f) * 0.015625f - 0.5f;
        float fx = floorf(xs);
        int x0 = min(max((int)fx, 0), 15), x1 = min(x0 + 1, 15);
        float wx = xs - fx;
        float gz = gd * 8.f - 0.5f;
        float fz = floorf(gz);
        int z0 = min(max((int)fz, 0), 7), z1 = min(z0 + 1, 7);
        float wz = gz - fz;

        float acc[12];
        #pragma unroll
        for (int c = 0; c < 12; c++) acc[c] = 0.f;
        #pragma unroll
        for (int zi = 0; zi < 2; zi++) {
            int z = zi ? z1 : z0;
            float wzf = zi ? wz : 1.f - wz;
            const float4* p0 = (const float4*)(gy + z * 196 + x0 * 12);
            const float4* p1 = (const float4*)(gy + z * 196 + x1 * 12);
            float w0 = wzf * (1.f - wx), w1 = wzf * wx;
            #pragma unroll
            for (int q = 0; q < 3; q++) {
                float4 a = p0[q], c4 = p1[q];
                acc[q * 4 + 0] += w0 * a.x + w1 * c4.x;
                acc[q * 4 + 1] += w0 * a.y + w1 * c4.y;
                acc[q * 4 + 2] += w0 * a.z + w1 * c4.z;
                acc[q * 4 + 3] += w0 * a.w + w1 * c4.w;
            }
        }
        O0[j] = fmaf(acc[0], r, fmaf(acc[1], g, fmaf(acc[2], bl, acc[3])));
        O1[j] = fmaf(acc[4], r, fmaf(acc[5], g, fmaf(acc[6], bl, acc[7])));
        O2[j] = fmaf(acc[8], r, fmaf(acc[9], g, fmaf(acc[10], bl, acc[11])));
    }

    *(float4*)(gd_out + (size_t)b * HW_ + rowoff) = make_float4(gdv[0], gdv[1], gdv[2], gdv[3]);
    float* fb = fin_out + (size_t)b * 3 * HW_;
    *(float4*)(fb + rowoff)           = make_float4(O0[0], O0[1], O0[2], O0[3]);
    *(float4*)(fb + HW_ + rowoff)     = make_float4(O1[0], O1[1], O1[2], O1[3]);
    *(float4*)(fb + 2 * HW_ + rowoff) = make_float4(O2[0], O2[1], O2[2], O2[3]);
}

extern "C" void kernel_launch(void* const* d_in, const int* in_sizes, int n_in,
                              void* d_out, int out_size, void* d_ws, size_t ws_size,
                              hipStream_t stream) {
    const float* lr   = (const float*)d_in[0];
    const float* fr   = (const float*)d_in[1];
    const float* sw0  = (const float*)d_in[2];  const float* sb0 = (const float*)d_in[3];
    const float* sw1  = (const float*)d_in[4];  const float* sb1 = (const float*)d_in[5];
    const float* sw2  = (const float*)d_in[6];  const float* sb2 = (const float*)d_in[7];
    const float* sw3  = (const float*)d_in[8];  const float* sb3 = (const float*)d_in[9];
    const float* lw0  = (const float*)d_in[10]; const float* lb0 = (const float*)d_in[11];
    const float* lw1  = (const float*)d_in[12]; const float* lb1 = (const float*)d_in[13];
    const float* gcw0 = (const float*)d_in[14]; const float* gcb0 = (const float*)d_in[15];
    const float* gcw1 = (const float*)d_in[16]; const float* gcb1 = (const float*)d_in[17];
    const float* fcw0 = (const float*)d_in[18]; const float* fcb0 = (const float*)d_in[19];
    const float* fcw1 = (const float*)d_in[20]; const float* fcb1 = (const float*)d_in[21];
    const float* fcw2 = (const float*)d_in[22]; const float* fcb2 = (const float*)d_in[23];
    const float* bgw  = (const float*)d_in[24]; const float* bgb = (const float*)d_in[25];
    const float* guw0 = (const float*)d_in[26]; const float* gub0 = (const float*)d_in[27];
    const float* guw1 = (const float*)d_in[28]; const float* gub1 = (const float*)d_in[29];

    float* ws = (float*)d_ws;
    float* ws3    = ws;            // [2,64,16,16]   32768
    float* loc0   = ws + 32768;    // [2,64,16,16]   32768
    float* loc    = ws + 65536;    // [2,64,16,16]   32768
    float* g0     = ws + 98304;    // [2,64,8,8]     8192
    float* h0     = ws + 106496;   // [2,256]        512
    float* grid_r = ws + 107008;   // [2,8,16,16,12] 49152

    float* gd_out  = (float*)d_out;             // [2,1024,1024]
    float* fin_out = (float*)d_out + 2 * HW_;   // [2,3,1024,1024]

    const int B = 2;

    k_splat<<<dim3(256, B), 256, 0, stream>>>(lr, sw0, sb0, sw1, sb1,
                                              sw2, sb2, sw3, sb3, ws3);
    k_loc0_gc0<<<dim3(80, B), 256, 0, stream>>>(ws3, lw0, lb0, loc0, gcw0, gcb0, g0);
    k_loc1_fc<<<dim3(96, B), 256, 0, stream>>>(loc0, lw1, lb1, loc, g0, gcw1, gcb1,
                                               fcw0, fcb0, h0);
    k_fc12bg<<<dim3(16, B), 256, 0, stream>>>(h0, fcw1, fcb1, fcw2, fcb2,
                                              loc, bgw, bgb, grid_r);
    guide_slice<<<dim3(1024, B), 256, 0, stream>>>(
        fr, grid_r, guw0, gub0, guw1, gub1, gd_out, fin_out);
}

// Round 13
// 104.061 us; speedup vs baseline: 1.2064x; 1.2064x over previous
//
#include <hip/hip_runtime.h>
#include <math.h>

#define HW_ (1024*1024)

__device__ __forceinline__ float wave_red(float a) {
    a += __shfl_xor(a, 1);  a += __shfl_xor(a, 2);  a += __shfl_xor(a, 4);
    a += __shfl_xor(a, 8);  a += __shfl_xor(a, 16); a += __shfl_xor(a, 32);
    return a;
}

// ============ fully-fused splat stack: lr -> s0 -> s1 -> s2 -> s3 (ws3) ============
// grid (256, B): each block owns ONE s3 output pixel (ty,tx), all 64 channels.
__global__ void k_splat(const float* __restrict__ lr,
                        const float* __restrict__ sw0, const float* __restrict__ sb0,
                        const float* __restrict__ sw1, const float* __restrict__ sb1,
                        const float* __restrict__ sw2, const float* __restrict__ sb2,
                        const float* __restrict__ sw3, const float* __restrict__ sb3,
                        float* __restrict__ ws3)
{
    __shared__ float lrs[3 * 31 * 32];   // 2976
    __shared__ float s0b[8 * 15 * 16];   // 1920
    __shared__ float s1b[16 * 7 * 8];    // 896
    __shared__ float s2b[32 * 9];        // 288
    __shared__ float w1s[1152];
    __shared__ float w2s[4608];
    int b = blockIdx.y;
    int ty = blockIdx.x >> 4, tx = blockIdx.x & 15;
    int t = threadIdx.x;

    for (int i = t; i < 2883; i += 256) {
        int c = i / 961, rem = i % 961, y = rem / 31, x = rem % 31;
        int gy = 16 * ty - 15 + y, gx = 16 * tx - 15 + x;
        float val = 0.f;
        if ((unsigned)gy < 256u && (unsigned)gx < 256u)
            val = lr[(((size_t)b * 3 + c) << 16) + (gy << 8) + gx];
        lrs[c * 992 + y * 32 + x] = val;
    }
    for (int i = t; i < 1152; i += 256) w1s[i] = sw1[i];
    for (int i = t; i < 4608; i += 256) w2s[i] = sw2[i];
    __syncthreads();

    for (int i = t; i < 1800; i += 256) {
        int c = i / 225, rem = i % 225, y = rem / 15, x = rem % 15;
        int gy = 8 * ty - 7 + y, gx = 8 * tx - 7 + x;
        float val = 0.f;
        if ((unsigned)gy < 128u && (unsigned)gx < 128u) {
            float acc = sb0[c];
            const float* wp = sw0 + c * 27;
            #pragma unroll
            for (int ci = 0; ci < 3; ci++) {
                const float* sp = lrs + ci * 992;
                #pragma unroll
                for (int kh = 0; kh < 3; kh++)
                    #pragma unroll
                    for (int kw = 0; kw < 3; kw++)
                        acc = fmaf(sp[(2 * y + kh) * 32 + 2 * x + kw],
                                   wp[ci * 9 + kh * 3 + kw], acc);
            }
            val = fmaxf(acc, 0.f);
        }
        s0b[c * 240 + y * 16 + x] = val;
    }
    __syncthreads();

    for (int i = t; i < 784; i += 256) {
        int c = i / 49, rem = i % 49, y = rem / 7, x = rem % 7;
        int gy = 4 * ty - 3 + y, gx = 4 * tx - 3 + x;
        float val = 0.f;
        if ((unsigned)gy < 64u && (unsigned)gx < 64u) {
            float acc = sb1[c];
            const float* wp = w1s + c * 72;
            #pragma unroll
            for (int ci = 0; ci < 8; ci++) {
                const float* sp = s0b + ci * 240;
                #pragma unroll
                for (int kh = 0; kh < 3; kh++)
                    #pragma unroll
                    for (int kw = 0; kw < 3; kw++)
                        acc = fmaf(sp[(2 * y + kh) * 16 + 2 * x + kw],
                                   wp[ci * 9 + kh * 3 + kw], acc);
            }
            val = fmaxf(acc, 0.f);
        }
        s1b[c * 56 + y * 8 + x] = val;
    }
    __syncthreads();

    for (int i = t; i < 288; i += 256) {
        int c = i / 9, rem = i % 9, y = rem / 3, x = rem % 3;
        int gy = 2 * ty - 1 + y, gx = 2 * tx - 1 + x;
        float val = 0.f;
        if ((unsigned)gy < 32u && (unsigned)gx < 32u) {
            float acc = sb2[c];
            const float* wp = w2s + c * 144;
            #pragma unroll
            for (int ci = 0; ci < 16; ci++) {
                const float* sp = s1b + ci * 56;
                #pragma unroll
                for (int kh = 0; kh < 3; kh++)
                    #pragma unroll
                    for (int kw = 0; kw < 3; kw++)
                        acc = fmaf(sp[(2 * y + kh) * 8 + 2 * x + kw],
                                   wp[ci * 9 + kh * 3 + kw], acc);
            }
            val = fmaxf(acc, 0.f);
        }
        s2b[c * 9 + y * 3 + x] = val;
    }
    __syncthreads();

    {
        int c = t >> 2, sub = t & 3;
        float acc = 0.f;
        const float* wp = sw3 + c * 288 + sub * 72;
        #pragma unroll
        for (int ci8 = 0; ci8 < 8; ci8++) {
            const float* sp = s2b + (sub * 8 + ci8) * 9;
            #pragma unroll
            for (int k = 0; k < 9; k++)
                acc = fmaf(sp[k], wp[ci8 * 9 + k], acc);
        }
        acc += __shfl_xor(acc, 1);
        acc += __shfl_xor(acc, 2);
        if (sub == 0)
            ws3[(((size_t)b * 64 + c) * 16 + ty) * 16 + tx] = fmaxf(acc + sb3[c], 0.f);
    }
}

// ---- lw0 || gcw0, full input map in LDS ([64][16][18]); weights via LDS; 4-acc ILP ----
// grid (80, B)
__global__ void k_loc0_gc0(const float* __restrict__ ws3,
                           const float* __restrict__ lw0, const float* __restrict__ lb0,
                           float* __restrict__ loc0,
                           const float* __restrict__ gcw0, const float* __restrict__ gcb0,
                           float* __restrict__ g0)
{
    __shared__ float smem[20736];        // inp 18432 + weights 2304
    float* inp = smem;
    float* wgt = smem + 18432;
    int b = blockIdx.y, t = threadIdx.x;

    for (int i = t; i < 2048; i += 256) {
        int ci = i >> 5, rem = i & 31;
        inp[ci * 288 + (rem >> 1) * 18 + (rem & 1) * 17] = 0.f;
    }
    {
        const float4* src = (const float4*)(ws3 + ((size_t)b << 14));
        #pragma unroll
        for (int k = 0; k < 16; k++) {
            int i = t + (k << 8);
            float4 vv = src[i];
            int flat = i << 2;
            float* d = inp + (flat >> 8) * 288 + ((flat >> 4) & 15) * 18 + (flat & 15) + 1;
            d[0] = vv.x; d[1] = vv.y; d[2] = vv.z; d[3] = vv.w;
        }
    }
    if (blockIdx.x < 64) {
        int co = blockIdx.x;
        if (t < 144) ((float4*)wgt)[t] = ((const float4*)(lw0 + co * 576))[t];
        __syncthreads();
        int ho = t >> 4, wo = t & 15;
        float a0 = 0.f, a1 = 0.f, a2 = 0.f, a3 = 0.f;
        for (int ci = 0; ci < 16; ci++) {
            #pragma unroll
            for (int kh = 0; kh < 3; kh++) {
                int hi = ho - 1 + kh;
                if ((unsigned)hi >= 16u) continue;
                const float* qa = inp + ci * 288 + hi * 18 + wo;
                const float* wa = wgt + ci * 9 + kh * 3;
                a0 = fmaf(qa[0], wa[0], a0); a0 = fmaf(qa[1], wa[1], a0); a0 = fmaf(qa[2], wa[2], a0);
                const float* qb = qa + 16 * 288; const float* wb2 = wa + 144;
                a1 = fmaf(qb[0], wb2[0], a1); a1 = fmaf(qb[1], wb2[1], a1); a1 = fmaf(qb[2], wb2[2], a1);
                const float* qc = qa + 32 * 288; const float* wc = wa + 288;
                a2 = fmaf(qc[0], wc[0], a2); a2 = fmaf(qc[1], wc[1], a2); a2 = fmaf(qc[2], wc[2], a2);
                const float* qd = qa + 48 * 288; const float* wd = wa + 432;
                a3 = fmaf(qd[0], wd[0], a3); a3 = fmaf(qd[1], wd[1], a3); a3 = fmaf(qd[2], wd[2], a3);
            }
        }
        float acc = lb0[co] + ((a0 + a1) + (a2 + a3));
        loc0[((size_t)(b * 64 + co) << 8) + t] = fmaxf(acc, 0.f);
    } else {
        int cb = (blockIdx.x - 64) << 2;
        for (int i = t; i < 2304; i += 256) wgt[i] = gcw0[cb * 576 + i];
        __syncthreads();
        int sub = t >> 6, co = cb + sub;
        int px = t & 63, ho = px >> 3, wo = px & 7;
        const float* wb = wgt + sub * 576;
        float a0 = 0.f, a1 = 0.f, a2 = 0.f, a3 = 0.f;
        for (int ci = 0; ci < 16; ci++) {
            #pragma unroll
            for (int kh = 0; kh < 3; kh++) {
                int hi = (ho << 1) - 1 + kh;
                if ((unsigned)hi >= 16u) continue;
                const float* qa = inp + ci * 288 + hi * 18 + (wo << 1);
                const float* wa = wb + ci * 9 + kh * 3;
                a0 = fmaf(qa[0], wa[0], a0); a0 = fmaf(qa[1], wa[1], a0); a0 = fmaf(qa[2], wa[2], a0);
                const float* qb = qa + 16 * 288; const float* wb2 = wa + 144;
                a1 = fmaf(qb[0], wb2[0], a1); a1 = fmaf(qb[1], wb2[1], a1); a1 = fmaf(qb[2], wb2[2], a1);
                const float* qc = qa + 32 * 288; const float* wc = wa + 288;
                a2 = fmaf(qc[0], wc[0], a2); a2 = fmaf(qc[1], wc[1], a2); a2 = fmaf(qc[2], wc[2], a2);
                const float* qd = qa + 48 * 288; const float* wd = wa + 432;
                a3 = fmaf(qd[0], wd[0], a3); a3 = fmaf(qd[1], wd[1], a3); a3 = fmaf(qd[2], wd[2], a3);
            }
        }
        float acc = gcb0[co] + ((a0 + a1) + (a2 + a3));
        g0[((size_t)(b * 64 + co) << 6) + px] = fmaxf(acc, 0.f);
    }
}

// ---- lw1 (no relu) || gcw1 (->v reshape order); LDS weights; 4-acc ILP. grid (68, B) ----
__global__ void k_loc1_gc1(const float* __restrict__ loc0,
                           const float* __restrict__ lw1, const float* __restrict__ lb1,
                           float* __restrict__ loc,
                           const float* __restrict__ g0,
                           const float* __restrict__ gcw1, const float* __restrict__ gcb1,
                           float* __restrict__ v)
{
    __shared__ float smem[19008];        // loc: inp 18432 + wloc 576 ; gc: inp 5120 + wgt 9216
    int b = blockIdx.y, t = threadIdx.x;
    if (blockIdx.x < 64) {
        float* inp = smem;               // [64][16][18]
        float* wloc = smem + 18432;      // 576
        int co = blockIdx.x;
        for (int i = t; i < 2048; i += 256) {
            int ci = i >> 5, rem = i & 31;
            inp[ci * 288 + (rem >> 1) * 18 + (rem & 1) * 17] = 0.f;
        }
        const float4* src = (const float4*)(loc0 + ((size_t)b << 14));
        #pragma unroll
        for (int k = 0; k < 16; k++) {
            int i = t + (k << 8);
            float4 vv = src[i];
            int flat = i << 2;
            float* d = inp + (flat >> 8) * 288 + ((flat >> 4) & 15) * 18 + (flat & 15) + 1;
            d[0] = vv.x; d[1] = vv.y; d[2] = vv.z; d[3] = vv.w;
        }
        if (t < 144) ((float4*)wloc)[t] = ((const float4*)(lw1 + co * 576))[t];
        __syncthreads();
        int ho = t >> 4, wo = t & 15;
        float a0 = 0.f, a1 = 0.f, a2 = 0.f, a3 = 0.f;
        for (int ci = 0; ci < 16; ci++) {
            #pragma unroll
            for (int kh = 0; kh < 3; kh++) {
                int hi = ho - 1 + kh;
                if ((unsigned)hi >= 16u) continue;
                const float* qa = inp + ci * 288 + hi * 18 + wo;
                const float* wa = wloc + ci * 9 + kh * 3;
                a0 = fmaf(qa[0], wa[0], a0); a0 = fmaf(qa[1], wa[1], a0); a0 = fmaf(qa[2], wa[2], a0);
                const float* qb = qa + 16 * 288; const float* wb2 = wa + 144;
                a1 = fmaf(qb[0], wb2[0], a1); a1 = fmaf(qb[1], wb2[1], a1); a1 = fmaf(qb[2], wb2[2], a1);
                const float* qc = qa + 32 * 288; const float* wc = wa + 288;
                a2 = fmaf(qc[0], wc[0], a2); a2 = fmaf(qc[1], wc[1], a2); a2 = fmaf(qc[2], wc[2], a2);
                const float* qd = qa + 48 * 288; const float* wd = wa + 432;
                a3 = fmaf(qd[0], wd[0], a3); a3 = fmaf(qd[1], wd[1], a3); a3 = fmaf(qd[2], wd[2], a3);
            }
        }
        loc[((size_t)(b * 64 + co) << 8) + t] = lb1[co] + ((a0 + a1) + (a2 + a3));  // no relu
    } else {
        float* inp = smem;               // [64][8][10] = 5120
        float* wgt = smem + 5120;        // 16co x 576 = 9216
        int cb = (blockIdx.x - 64) << 4;
        for (int i = t; i < 1024; i += 256) {
            int ci = i >> 4, rem = i & 15;
            inp[ci * 80 + (rem >> 1) * 10 + (rem & 1) * 9] = 0.f;
        }
        const float4* src = (const float4*)(g0 + ((size_t)b << 12));
        #pragma unroll
        for (int k = 0; k < 4; k++) {
            int i = t + (k << 8);
            float4 vv = src[i];
            int flat = i << 2;
            float* d = inp + (flat >> 6) * 80 + ((flat >> 3) & 7) * 10 + (flat & 7) + 1;
            d[0] = vv.x; d[1] = vv.y; d[2] = vv.z; d[3] = vv.w;
        }
        for (int i = t; i < 9216; i += 256) wgt[i] = gcw1[cb * 576 + i];
        __syncthreads();
        int sub = t >> 4, co = cb + sub;
        int px = t & 15, ho = px >> 2, wo = px & 3;
        const float* wb = wgt + sub * 576;
        float a0 = 0.f, a1 = 0.f, a2 = 0.f, a3 = 0.f;
        for (int ci = 0; ci < 16; ci++) {
            #pragma unroll
            for (int kh = 0; kh < 3; kh++) {
                int hi = (ho << 1) - 1 + kh;
                if ((unsigned)hi >= 8u) continue;
                const float* qa = inp + ci * 80 + hi * 10 + (wo << 1);
                const float* wa = wb + ci * 9 + kh * 3;
                a0 = fmaf(qa[0], wa[0], a0); a0 = fmaf(qa[1], wa[1], a0); a0 = fmaf(qa[2], wa[2], a0);
                const float* qb = qa + 16 * 80; const float* wb2 = wa + 144;
                a1 = fmaf(qb[0], wb2[0], a1); a1 = fmaf(qb[1], wb2[1], a1); a1 = fmaf(qb[2], wb2[2], a1);
                const float* qc = qa + 32 * 80; const float* wc = wa + 288;
                a2 = fmaf(qc[0], wc[0], a2); a2 = fmaf(qc[1], wc[1], a2); a2 = fmaf(qc[2], wc[2], a2);
                const float* qd = qa + 48 * 80; const float* wd = wa + 432;
                a3 = fmaf(qd[0], wd[0], a3); a3 = fmaf(qd[1], wd[1], a3); a3 = fmaf(qd[2], wd[2], a3);
            }
        }
        float acc = gcb1[co] + ((a0 + a1) + (a2 + a3));
        v[((size_t)b << 10) + (co << 4) + px] = fmaxf(acc, 0.f);
    }
}

// -------- FC0: wave-per-output GEMV 1024 -> 256, relu. grid 128 x 256thr --------
__global__ void k_fc0(const float* __restrict__ in, const float* __restrict__ w,
                      const float* __restrict__ bias, float* __restrict__ out)
{
    int gw = (blockIdx.x * blockDim.x + threadIdx.x) >> 6;   // [0, 512)
    int lane = threadIdx.x & 63;
    int b = gw >> 8, o = gw & 255;
    const float4* wr = (const float4*)(w + o * 1024);
    const float4* vr = (const float4*)(in + b * 1024);
    float acc = 0.f;
    #pragma unroll
    for (int i = 0; i < 4; i++) {
        float4 a = wr[i * 64 + lane];
        float4 x = vr[i * 64 + lane];
        acc += a.x * x.x + a.y * x.y + a.z * x.z + a.w * x.w;
    }
    acc = wave_red(acc);
    if (lane == 0) out[b * 256 + o] = fmaxf(acc + bias[o], 0.f);
}

// ------- fc1 + fc2 (redundant, coalesced) + fusion + bg conv (bgw in LDS). grid (16,B) -------
__global__ void k_fc12bg(const float* __restrict__ h0,
                         const float* __restrict__ fcw1, const float* __restrict__ fcb1,
                         const float* __restrict__ fcw2, const float* __restrict__ fcb2,
                         const float* __restrict__ loc,
                         const float* __restrict__ bgw, const float* __restrict__ bgb,
                         float* __restrict__ grid_r)
{
    __shared__ float h0s[256];
    __shared__ float h1s[128];
    __shared__ float gvs[64];
    __shared__ float fus[1024];          // [64ch][16pix]
    __shared__ float bgws[96 * 65];      // pad-65 rows
    int b = blockIdx.y, r = blockIdx.x;
    int t = threadIdx.x, lane = t & 63, wv = t >> 6;

    h0s[t] = h0[b * 256 + t];
    for (int i = t; i < 6144; i += 256) bgws[(i >> 6) * 65 + (i & 63)] = bgw[i];
    __syncthreads();
    {
        float4 x4 = ((float4*)h0s)[lane];
        #pragma unroll 4
        for (int i = 0; i < 32; i++) {
            int o = (wv << 5) + i;
            float4 a = ((const float4*)(fcw1 + o * 256))[lane];
            float acc = a.x * x4.x + a.y * x4.y + a.z * x4.z + a.w * x4.w;
            acc = wave_red(acc);
            if (lane == 0) h1s[o] = fmaxf(acc + fcb1[o], 0.f);
        }
    }
    __syncthreads();
    {
        float2 x2 = ((float2*)h1s)[lane];
        #pragma unroll 4
        for (int i = 0; i < 16; i++) {
            int o = (wv << 4) + i;
            float2 a = ((const float2*)(fcw2 + o * 128))[lane];
            float acc = a.x * x2.x + a.y * x2.y;
            acc = wave_red(acc);
            if (lane == 0) gvs[o] = acc + fcb2[o];
        }
    }
    __syncthreads();
    #pragma unroll
    for (int i = 0; i < 4; i++) {
        int idx = t + (i << 8);
        int c = idx >> 4, p = idx & 15;
        fus[idx] = fmaxf(loc[(((size_t)b * 64 + c) * 16 + r) * 16 + p] + gvs[c], 0.f);
    }
    __syncthreads();
    {
        int p = t & 15, cg = t >> 4;
        float acc6[6];
        #pragma unroll
        for (int j = 0; j < 6; j++) acc6[j] = bgb[cg + (j << 4)];
        #pragma unroll 8
        for (int k = 0; k < 64; k++) {
            float f = fus[k * 16 + p];
            #pragma unroll
            for (int j = 0; j < 6; j++)
                acc6[j] += bgws[(cg + (j << 4)) * 65 + k] * f;
        }
        #pragma unroll
        for (int j = 0; j < 6; j++) {
            int co = cg + (j << 4);
            int c12 = co >> 3, d = co & 7;
            grid_r[(((((size_t)b * 8 + d) * 16 + r) * 16 + p) * 12) + c12] = acc6[j];
        }
    }
}

// ------- fused guide + slice + apply: one image row per block, 4 px/thread -------
__global__ void guide_slice(const float* __restrict__ fr, const float* __restrict__ grid_r,
                            const float* __restrict__ guw0, const float* __restrict__ gub0,
                            const float* __restrict__ guw1, const float* __restrict__ gub1,
                            float* __restrict__ gd_out, float* __restrict__ fin_out)
{
    __shared__ float gy[8 * 196];        // z-stride 196 (4 mod 32): conflict-free z
    int y = blockIdx.x, b = blockIdx.y;
    int t = threadIdx.x;

    float ys = (y + 0.5f) * 0.015625f - 0.5f;
    float fy = floorf(ys);
    int y0 = min(max((int)fy, 0), 15), y1 = min(y0 + 1, 15);
    float wy = ys - fy;

    const float* gb = grid_r + (size_t)b * 24576;
    for (int i = t; i < 1536; i += 256) {
        int z = i / 192, rem = i - z * 192;
        float a = gb[z * 3072 + y0 * 192 + rem];
        float c = gb[z * 3072 + y1 * 192 + rem];
        gy[z * 196 + rem] = a + wy * (c - a);
    }
    __syncthreads();

    int rowoff = (y << 10) + (t << 2);
    const float* frb = fr + (size_t)b * 3 * HW_;
    float4 R4 = *(const float4*)(frb + rowoff);
    float4 G4 = *(const float4*)(frb + HW_ + rowoff);
    float4 B4 = *(const float4*)(frb + 2 * HW_ + rowoff);
    float rr[4] = {R4.x, R4.y, R4.z, R4.w};
    float gg[4] = {G4.x, G4.y, G4.z, G4.w};
    float bb[4] = {B4.x, B4.y, B4.z, B4.w};
    float gdv[4], O0[4], O1[4], O2[4];

    #pragma unroll
    for (int j = 0; j < 4; j++) {
        float r = rr[j], g = gg[j], bl = bb[j];
        float s = gub1[0];
        #pragma unroll
        for (int c = 0; c < 16; c++) {
            float h = fmaf(guw0[c * 3], r, fmaf(guw0[c * 3 + 1], g,
                      fmaf(guw0[c * 3 + 2], bl, gub0[c])));
            s = fmaf(guw1[c], fmaxf(h, 0.f), s);
        }
        float gd = 1.f / (1.f + __expf(-s));
        gdv[j] = gd;

        int x = (t << 2) + j;
        float xs = (x + 0.5f) * 0.015625f - 0.5f;
        float fx = floorf(xs);
        int x0 = min(max((int)fx, 0), 15), x1 = min(x0 + 1, 15);
        float wx = xs - fx;
        float gz = gd * 8.f - 0.5f;
        float fz = floorf(gz);
        int z0 = min(max((int)fz, 0), 7), z1 = min(z0 + 1, 7);
        float wz = gz - fz;

        float acc[12];
        #pragma unroll
        for (int c = 0; c < 12; c++) acc[c] = 0.f;
        #pragma unroll
        for (int zi = 0; zi < 2; zi++) {
            int z = zi ? z1 : z0;
            float wzf = zi ? wz : 1.f - wz;
            const float4* p0 = (const float4*)(gy + z * 196 + x0 * 12);
            const float4* p1 = (const float4*)(gy + z * 196 + x1 * 12);
            float w0 = wzf * (1.f - wx), w1 = wzf * wx;
            #pragma unroll
            for (int q = 0; q < 3; q++) {
                float4 a = p0[q], c4 = p1[q];
                acc[q * 4 + 0] += w0 * a.x + w1 * c4.x;
                acc[q * 4 + 1] += w0 * a.y + w1 * c4.y;
                acc[q * 4 + 2] += w0 * a.z + w1 * c4.z;
                acc[q * 4 + 3] += w0 * a.w + w1 * c4.w;
            }
        }
        O0[j] = fmaf(acc[0], r, fmaf(acc[1], g, fmaf(acc[2], bl, acc[3])));
        O1[j] = fmaf(acc[4], r, fmaf(acc[5], g, fmaf(acc[6], bl, acc[7])));
        O2[j] = fmaf(acc[8], r, fmaf(acc[9], g, fmaf(acc[10], bl, acc[11])));
    }

    *(float4*)(gd_out + (size_t)b * HW_ + rowoff) = make_float4(gdv[0], gdv[1], gdv[2], gdv[3]);
    float* fb = fin_out + (size_t)b * 3 * HW_;
    *(float4*)(fb + rowoff)           = make_float4(O0[0], O0[1], O0[2], O0[3]);
    *(float4*)(fb + HW_ + rowoff)     = make_float4(O1[0], O1[1], O1[2], O1[3]);
    *(float4*)(fb + 2 * HW_ + rowoff) = make_float4(O2[0], O2[1], O2[2], O2[3]);
}

extern "C" void kernel_launch(void* const* d_in, const int* in_sizes, int n_in,
                              void* d_out, int out_size, void* d_ws, size_t ws_size,
                              hipStream_t stream) {
    const float* lr   = (const float*)d_in[0];
    const float* fr   = (const float*)d_in[1];
    const float* sw0  = (const float*)d_in[2];  const float* sb0 = (const float*)d_in[3];
    const float* sw1  = (const float*)d_in[4];  const float* sb1 = (const float*)d_in[5];
    const float* sw2  = (const float*)d_in[6];  const float* sb2 = (const float*)d_in[7];
    const float* sw3  = (const float*)d_in[8];  const float* sb3 = (const float*)d_in[9];
    const float* lw0  = (const float*)d_in[10]; const float* lb0 = (const float*)d_in[11];
    const float* lw1  = (const float*)d_in[12]; const float* lb1 = (const float*)d_in[13];
    const float* gcw0 = (const float*)d_in[14]; const float* gcb0 = (const float*)d_in[15];
    const float* gcw1 = (const float*)d_in[16]; const float* gcb1 = (const float*)d_in[17];
    const float* fcw0 = (const float*)d_in[18]; const float* fcb0 = (const float*)d_in[19];
    const float* fcw1 = (const float*)d_in[20]; const float* fcb1 = (const float*)d_in[21];
    const float* fcw2 = (const float*)d_in[22]; const float* fcb2 = (const float*)d_in[23];
    const float* bgw  = (const float*)d_in[24]; const float* bgb = (const float*)d_in[25];
    const float* guw0 = (const float*)d_in[26]; const float* gub0 = (const float*)d_in[27];
    const float* guw1 = (const float*)d_in[28]; const float* gub1 = (const float*)d_in[29];

    float* ws = (float*)d_ws;
    float* ws3    = ws;            // [2,64,16,16]   32768
    float* loc0   = ws + 32768;    // [2,64,16,16]   32768
    float* loc    = ws + 65536;    // [2,64,16,16]   32768
    float* g0     = ws + 98304;    // [2,64,8,8]     8192
    float* v      = ws + 106496;   // [2,1024]       2048
    float* h0     = ws + 108544;   // [2,256]        512
    float* grid_r = ws + 109056;   // [2,8,16,16,12] 49152

    float* gd_out  = (float*)d_out;             // [2,1024,1024]
    float* fin_out = (float*)d_out + 2 * HW_;   // [2,3,1024,1024]

    const int B = 2;

    k_splat<<<dim3(256, B), 256, 0, stream>>>(lr, sw0, sb0, sw1, sb1,
                                              sw2, sb2, sw3, sb3, ws3);
    k_loc0_gc0<<<dim3(80, B), 256, 0, stream>>>(ws3, lw0, lb0, loc0, gcw0, gcb0, g0);
    k_loc1_gc1<<<dim3(68, B), 256, 0, stream>>>(loc0, lw1, lb1, loc, g0, gcw1, gcb1, v);
    k_fc0<<<dim3(128), 256, 0, stream>>>(v, fcw0, fcb0, h0);
    k_fc12bg<<<dim3(16, B), 256, 0, stream>>>(h0, fcw1, fcb1, fcw2, fcb2,
                                              loc, bgw, bgb, grid_r);
    guide_slice<<<dim3(1024, B), 256, 0, stream>>>(
        fr, grid_r, guw0, gub0, guw1, gub1, gd_out, fin_out);
}

// Round 14
// 85.634 us; speedup vs baseline: 1.4660x; 1.2152x over previous
//
#include <hip/hip_runtime.h>
#include <math.h>

#define HW_ (1024*1024)

__device__ __forceinline__ float wave_red(float a) {
    a += __shfl_xor(a, 1);  a += __shfl_xor(a, 2);  a += __shfl_xor(a, 4);
    a += __shfl_xor(a, 8);  a += __shfl_xor(a, 16); a += __shfl_xor(a, 32);
    return a;
}

// ============ fully-fused splat stack: lr -> s0 -> s1 -> s2 -> s3 (ws3) ============
// grid (256, B): each block owns ONE s3 output pixel (ty,tx), all 64 channels.
__global__ void k_splat(const float* __restrict__ lr,
                        const float* __restrict__ sw0, const float* __restrict__ sb0,
                        const float* __restrict__ sw1, const float* __restrict__ sb1,
                        const float* __restrict__ sw2, const float* __restrict__ sb2,
                        const float* __restrict__ sw3, const float* __restrict__ sb3,
                        float* __restrict__ ws3)
{
    __shared__ float lrs[3 * 31 * 32];   // 2976
    __shared__ float s0b[8 * 15 * 16];   // 1920
    __shared__ float s1b[16 * 7 * 8];    // 896
    __shared__ float s2b[32 * 9];        // 288
    __shared__ float w1s[1152];
    __shared__ float w2s[4608];
    int b = blockIdx.y;
    int ty = blockIdx.x >> 4, tx = blockIdx.x & 15;
    int t = threadIdx.x;

    for (int i = t; i < 2883; i += 256) {
        int c = i / 961, rem = i % 961, y = rem / 31, x = rem % 31;
        int gy = 16 * ty - 15 + y, gx = 16 * tx - 15 + x;
        float val = 0.f;
        if ((unsigned)gy < 256u && (unsigned)gx < 256u)
            val = lr[(((size_t)b * 3 + c) << 16) + (gy << 8) + gx];
        lrs[c * 992 + y * 32 + x] = val;
    }
    for (int i = t; i < 1152; i += 256) w1s[i] = sw1[i];
    for (int i = t; i < 4608; i += 256) w2s[i] = sw2[i];
    __syncthreads();

    for (int i = t; i < 1800; i += 256) {
        int c = i / 225, rem = i % 225, y = rem / 15, x = rem % 15;
        int gy = 8 * ty - 7 + y, gx = 8 * tx - 7 + x;
        float val = 0.f;
        if ((unsigned)gy < 128u && (unsigned)gx < 128u) {
            float acc = sb0[c];
            const float* wp = sw0 + c * 27;
            #pragma unroll
            for (int ci = 0; ci < 3; ci++) {
                const float* sp = lrs + ci * 992;
                #pragma unroll
                for (int kh = 0; kh < 3; kh++)
                    #pragma unroll
                    for (int kw = 0; kw < 3; kw++)
                        acc = fmaf(sp[(2 * y + kh) * 32 + 2 * x + kw],
                                   wp[ci * 9 + kh * 3 + kw], acc);
            }
            val = fmaxf(acc, 0.f);
        }
        s0b[c * 240 + y * 16 + x] = val;
    }
    __syncthreads();

    for (int i = t; i < 784; i += 256) {
        int c = i / 49, rem = i % 49, y = rem / 7, x = rem % 7;
        int gy = 4 * ty - 3 + y, gx = 4 * tx - 3 + x;
        float val = 0.f;
        if ((unsigned)gy < 64u && (unsigned)gx < 64u) {
            float acc = sb1[c];
            const float* wp = w1s + c * 72;
            #pragma unroll
            for (int ci = 0; ci < 8; ci++) {
                const float* sp = s0b + ci * 240;
                #pragma unroll
                for (int kh = 0; kh < 3; kh++)
                    #pragma unroll
                    for (int kw = 0; kw < 3; kw++)
                        acc = fmaf(sp[(2 * y + kh) * 16 + 2 * x + kw],
                                   wp[ci * 9 + kh * 3 + kw], acc);
            }
            val = fmaxf(acc, 0.f);
        }
        s1b[c * 56 + y * 8 + x] = val;
    }
    __syncthreads();

    for (int i = t; i < 288; i += 256) {
        int c = i / 9, rem = i % 9, y = rem / 3, x = rem % 3;
        int gy = 2 * ty - 1 + y, gx = 2 * tx - 1 + x;
        float val = 0.f;
        if ((unsigned)gy < 32u && (unsigned)gx < 32u) {
            float acc = sb2[c];
            const float* wp = w2s + c * 144;
            #pragma unroll
            for (int ci = 0; ci < 16; ci++) {
                const float* sp = s1b + ci * 56;
                #pragma unroll
                for (int kh = 0; kh < 3; kh++)
                    #pragma unroll
                    for (int kw = 0; kw < 3; kw++)
                        acc = fmaf(sp[(2 * y + kh) * 8 + 2 * x + kw],
                                   wp[ci * 9 + kh * 3 + kw], acc);
            }
            val = fmaxf(acc, 0.f);
        }
        s2b[c * 9 + y * 3 + x] = val;
    }
    __syncthreads();

    {
        int c = t >> 2, sub = t & 3;
        float acc = 0.f;
        const float* wp = sw3 + c * 288 + sub * 72;
        #pragma unroll
        for (int ci8 = 0; ci8 < 8; ci8++) {
            const float* sp = s2b + (sub * 8 + ci8) * 9;
            #pragma unroll
            for (int k = 0; k < 9; k++)
                acc = fmaf(sp[k], wp[ci8 * 9 + k], acc);
        }
        acc += __shfl_xor(acc, 1);
        acc += __shfl_xor(acc, 2);
        if (sub == 0)
            ws3[(((size_t)b * 64 + c) * 16 + ty) * 16 + tx] = fmaxf(acc + sb3[c], 0.f);
    }
}

// ---- lw0 || gcw0, full input map in LDS ([64][16][18]); weights via LDS; 4-acc ILP ----
// grid (80, B)
__global__ void k_loc0_gc0(const float* __restrict__ ws3,
                           const float* __restrict__ lw0, const float* __restrict__ lb0,
                           float* __restrict__ loc0,
                           const float* __restrict__ gcw0, const float* __restrict__ gcb0,
                           float* __restrict__ g0)
{
    __shared__ float smem[20736];        // inp 18432 + weights 2304
    float* inp = smem;
    float* wgt = smem + 18432;
    int b = blockIdx.y, t = threadIdx.x;

    for (int i = t; i < 2048; i += 256) {
        int ci = i >> 5, rem = i & 31;
        inp[ci * 288 + (rem >> 1) * 18 + (rem & 1) * 17] = 0.f;
    }
    {
        const float4* src = (const float4*)(ws3 + ((size_t)b << 14));
        #pragma unroll
        for (int k = 0; k < 16; k++) {
            int i = t + (k << 8);
            float4 vv = src[i];
            int flat = i << 2;
            float* d = inp + (flat >> 8) * 288 + ((flat >> 4) & 15) * 18 + (flat & 15) + 1;
            d[0] = vv.x; d[1] = vv.y; d[2] = vv.z; d[3] = vv.w;
        }
    }
    if (blockIdx.x < 64) {
        int co = blockIdx.x;
        if (t < 144) ((float4*)wgt)[t] = ((const float4*)(lw0 + co * 576))[t];
        __syncthreads();
        int ho = t >> 4, wo = t & 15;
        float a0 = 0.f, a1 = 0.f, a2 = 0.f, a3 = 0.f;
        for (int ci = 0; ci < 16; ci++) {
            #pragma unroll
            for (int kh = 0; kh < 3; kh++) {
                int hi = ho - 1 + kh;
                if ((unsigned)hi >= 16u) continue;
                const float* qa = inp + ci * 288 + hi * 18 + wo;
                const float* wa = wgt + ci * 9 + kh * 3;
                a0 = fmaf(qa[0], wa[0], a0); a0 = fmaf(qa[1], wa[1], a0); a0 = fmaf(qa[2], wa[2], a0);
                const float* qb = qa + 16 * 288; const float* wb2 = wa + 144;
                a1 = fmaf(qb[0], wb2[0], a1); a1 = fmaf(qb[1], wb2[1], a1); a1 = fmaf(qb[2], wb2[2], a1);
                const float* qc = qa + 32 * 288; const float* wc = wa + 288;
                a2 = fmaf(qc[0], wc[0], a2); a2 = fmaf(qc[1], wc[1], a2); a2 = fmaf(qc[2], wc[2], a2);
                const float* qd = qa + 48 * 288; const float* wd = wa + 432;
                a3 = fmaf(qd[0], wd[0], a3); a3 = fmaf(qd[1], wd[1], a3); a3 = fmaf(qd[2], wd[2], a3);
            }
        }
        float acc = lb0[co] + ((a0 + a1) + (a2 + a3));
        loc0[((size_t)(b * 64 + co) << 8) + t] = fmaxf(acc, 0.f);
    } else {
        int cb = (blockIdx.x - 64) << 2;
        for (int i = t; i < 2304; i += 256) wgt[i] = gcw0[cb * 576 + i];
        __syncthreads();
        int sub = t >> 6, co = cb + sub;
        int px = t & 63, ho = px >> 3, wo = px & 7;
        const float* wb = wgt + sub * 576;
        float a0 = 0.f, a1 = 0.f, a2 = 0.f, a3 = 0.f;
        for (int ci = 0; ci < 16; ci++) {
            #pragma unroll
            for (int kh = 0; kh < 3; kh++) {
                int hi = (ho << 1) - 1 + kh;
                if ((unsigned)hi >= 16u) continue;
                const float* qa = inp + ci * 288 + hi * 18 + (wo << 1);
                const float* wa = wb + ci * 9 + kh * 3;
                a0 = fmaf(qa[0], wa[0], a0); a0 = fmaf(qa[1], wa[1], a0); a0 = fmaf(qa[2], wa[2], a0);
                const float* qb = qa + 16 * 288; const float* wb2 = wa + 144;
                a1 = fmaf(qb[0], wb2[0], a1); a1 = fmaf(qb[1], wb2[1], a1); a1 = fmaf(qb[2], wb2[2], a1);
                const float* qc = qa + 32 * 288; const float* wc = wa + 288;
                a2 = fmaf(qc[0], wc[0], a2); a2 = fmaf(qc[1], wc[1], a2); a2 = fmaf(qc[2], wc[2], a2);
                const float* qd = qa + 48 * 288; const float* wd = wa + 432;
                a3 = fmaf(qd[0], wd[0], a3); a3 = fmaf(qd[1], wd[1], a3); a3 = fmaf(qd[2], wd[2], a3);
            }
        }
        float acc = gcb0[co] + ((a0 + a1) + (a2 + a3));
        g0[((size_t)(b * 64 + co) << 6) + px] = fmaxf(acc, 0.f);
    }
}

// ---- lw1 (no relu) || gcw1 (->v reshape order); LDS weights; 4-acc ILP. grid (68, B) ----
__global__ void k_loc1_gc1(const float* __restrict__ loc0,
                           const float* __restrict__ lw1, const float* __restrict__ lb1,
                           float* __restrict__ loc,
                           const float* __restrict__ g0,
                           const float* __restrict__ gcw1, const float* __restrict__ gcb1,
                           float* __restrict__ v)
{
    __shared__ float smem[19008];        // loc: inp 18432 + wloc 576 ; gc: inp 5120 + wgt 9216
    int b = blockIdx.y, t = threadIdx.x;
    if (blockIdx.x < 64) {
        float* inp = smem;               // [64][16][18]
        float* wloc = smem + 18432;      // 576
        int co = blockIdx.x;
        for (int i = t; i < 2048; i += 256) {
            int ci = i >> 5, rem = i & 31;
            inp[ci * 288 + (rem >> 1) * 18 + (rem & 1) * 17] = 0.f;
        }
        const float4* src = (const float4*)(loc0 + ((size_t)b << 14));
        #pragma unroll
        for (int k = 0; k < 16; k++) {
            int i = t + (k << 8);
            float4 vv = src[i];
            int flat = i << 2;
            float* d = inp + (flat >> 8) * 288 + ((flat >> 4) & 15) * 18 + (flat & 15) + 1;
            d[0] = vv.x; d[1] = vv.y; d[2] = vv.z; d[3] = vv.w;
        }
        if (t < 144) ((float4*)wloc)[t] = ((const float4*)(lw1 + co * 576))[t];
        __syncthreads();
        int ho = t >> 4, wo = t & 15;
        float a0 = 0.f, a1 = 0.f, a2 = 0.f, a3 = 0.f;
        for (int ci = 0; ci < 16; ci++) {
            #pragma unroll
            for (int kh = 0; kh < 3; kh++) {
                int hi = ho - 1 + kh;
                if ((unsigned)hi >= 16u) continue;
                const float* qa = inp + ci * 288 + hi * 18 + wo;
                const float* wa = wloc + ci * 9 + kh * 3;
                a0 = fmaf(qa[0], wa[0], a0); a0 = fmaf(qa[1], wa[1], a0); a0 = fmaf(qa[2], wa[2], a0);
                const float* qb = qa + 16 * 288; const float* wb2 = wa + 144;
                a1 = fmaf(qb[0], wb2[0], a1); a1 = fmaf(qb[1], wb2[1], a1); a1 = fmaf(qb[2], wb2[2], a1);
                const float* qc = qa + 32 * 288; const float* wc = wa + 288;
                a2 = fmaf(qc[0], wc[0], a2); a2 = fmaf(qc[1], wc[1], a2); a2 = fmaf(qc[2], wc[2], a2);
                const float* qd = qa + 48 * 288; const float* wd = wa + 432;
                a3 = fmaf(qd[0], wd[0], a3); a3 = fmaf(qd[1], wd[1], a3); a3 = fmaf(qd[2], wd[2], a3);
            }
        }
        loc[((size_t)(b * 64 + co) << 8) + t] = lb1[co] + ((a0 + a1) + (a2 + a3));  // no relu
    } else {
        float* inp = smem;               // [64][8][10] = 5120
        float* wgt = smem + 5120;        // 16co x 576 = 9216
        int cb = (blockIdx.x - 64) << 4;
        for (int i = t; i < 1024; i += 256) {
            int ci = i >> 4, rem = i & 15;
            inp[ci * 80 + (rem >> 1) * 10 + (rem & 1) * 9] = 0.f;
        }
        const float4* src = (const float4*)(g0 + ((size_t)b << 12));
        #pragma unroll
        for (int k = 0; k < 4; k++) {
            int i = t + (k << 8);
            float4 vv = src[i];
            int flat = i << 2;
            float* d = inp + (flat >> 6) * 80 + ((flat >> 3) & 7) * 10 + (flat & 7) + 1;
            d[0] = vv.x; d[1] = vv.y; d[2] = vv.z; d[3] = vv.w;
        }
        for (int i = t; i < 9216; i += 256) wgt[i] = gcw1[cb * 576 + i];
        __syncthreads();
        int sub = t >> 4, co = cb + sub;
        int px = t & 15, ho = px >> 2, wo = px & 3;
        const float* wb = wgt + sub * 576;
        float a0 = 0.f, a1 = 0.f, a2 = 0.f, a3 = 0.f;
        for (int ci = 0; ci < 16; ci++) {
            #pragma unroll
            for (int kh = 0; kh < 3; kh++) {
                int hi = (ho << 1) - 1 + kh;
                if ((unsigned)hi >= 8u) continue;
                const float* qa = inp + ci * 80 + hi * 10 + (wo << 1);
                const float* wa = wb + ci * 9 + kh * 3;
                a0 = fmaf(qa[0], wa[0], a0); a0 = fmaf(qa[1], wa[1], a0); a0 = fmaf(qa[2], wa[2], a0);
                const float* qb = qa + 16 * 80; const float* wb2 = wa + 144;
                a1 = fmaf(qb[0], wb2[0], a1); a1 = fmaf(qb[1], wb2[1], a1); a1 = fmaf(qb[2], wb2[2], a1);
                const float* qc = qa + 32 * 80; const float* wc = wa + 288;
                a2 = fmaf(qc[0], wc[0], a2); a2 = fmaf(qc[1], wc[1], a2); a2 = fmaf(qc[2], wc[2], a2);
                const float* qd = qa + 48 * 80; const float* wd = wa + 432;
                a3 = fmaf(qd[0], wd[0], a3); a3 = fmaf(qd[1], wd[1], a3); a3 = fmaf(qd[2], wd[2], a3);
            }
        }
        float acc = gcb1[co] + ((a0 + a1) + (a2 + a3));
        v[((size_t)b << 10) + (co << 4) + px] = fmaxf(acc, 0.f);
    }
}

// -------- FC0: wave-per-output GEMV 1024 -> 256, relu. grid 128 x 256thr --------
__global__ void k_fc0(const float* __restrict__ in, const float* __restrict__ w,
                      const float* __restrict__ bias, float* __restrict__ out)
{
    int gw = (blockIdx.x * blockDim.x + threadIdx.x) >> 6;   // [0, 512)
    int lane = threadIdx.x & 63;
    int b = gw >> 8, o = gw & 255;
    const float4* wr = (const float4*)(w + o * 1024);
    const float4* vr = (const float4*)(in + b * 1024);
    float acc = 0.f;
    #pragma unroll
    for (int i = 0; i < 4; i++) {
        float4 a = wr[i * 64 + lane];
        float4 x = vr[i * 64 + lane];
        acc += a.x * x.x + a.y * x.y + a.z * x.z + a.w * x.w;
    }
    acc = wave_red(acc);
    if (lane == 0) out[b * 256 + o] = fmaxf(acc + bias[o], 0.f);
}

// ------- fc1 + fc2 (LDS-staged weights, thread-per-output) + fusion + bg. grid (16,B) -------
// fc1/fc2 weights staged chunk-wise into LDS with fully-parallel coalesced float4 loads
// (high MLP, no shfl-chain stalls); dot products read LDS rows (pad-66/130: 2-way only).
__global__ void k_fc12bg(const float* __restrict__ h0,
                         const float* __restrict__ fcw1, const float* __restrict__ fcb1,
                         const float* __restrict__ fcw2, const float* __restrict__ fcb2,
                         const float* __restrict__ loc,
                         const float* __restrict__ bgw, const float* __restrict__ bgb,
                         float* __restrict__ grid_r)
{
    __shared__ float smem[15392];
    float* wst   = smem;            // 8448: fc1 chunks [128][66], fc2 [64][130]; later fus
    float* bgws  = smem + 8448;     // 6240 (96 rows x pad65)
    float* h0s   = smem + 14688;    // 256
    float* h1s   = smem + 14944;    // 128
    float* gvs   = smem + 15072;    // 64
    float* parts = smem + 15136;    // 256
    float* fus   = smem;            // reuse wst region after fc2

    int b = blockIdx.y, r = blockIdx.x;
    int t = threadIdx.x;

    h0s[t] = h0[b * 256 + t];
    for (int i = t; i < 6144; i += 256) bgws[(i >> 6) * 65 + (i & 63)] = bgw[i];

    // ---- fc1: 256 -> 128. 4 k-chunks of 64; o = t&127, k-half = (t>>7)*32 ----
    float acc1 = 0.f;
    int o1 = t & 127, kh2 = (t >> 7) << 5;
    for (int cc = 0; cc < 4; cc++) {
        __syncthreads();                 // wst safe to overwrite
        for (int i = t; i < 2048; i += 256) {
            int row = i >> 4, fc = i & 15;
            float4 w4 = ((const float4*)fcw1)[row * 64 + cc * 16 + fc];
            float* d = wst + row * 66 + (fc << 2);
            d[0] = w4.x; d[1] = w4.y; d[2] = w4.z; d[3] = w4.w;
        }
        __syncthreads();
        const float* wr = wst + o1 * 66 + kh2;
        const float* hr = h0s + cc * 64 + kh2;
        float a0 = 0.f, a1 = 0.f, a2 = 0.f, a3 = 0.f;
        #pragma unroll
        for (int k = 0; k < 32; k += 4) {
            a0 = fmaf(wr[k], hr[k], a0);
            a1 = fmaf(wr[k + 1], hr[k + 1], a1);
            a2 = fmaf(wr[k + 2], hr[k + 2], a2);
            a3 = fmaf(wr[k + 3], hr[k + 3], a3);
        }
        acc1 += (a0 + a1) + (a2 + a3);
    }
    __syncthreads();
    parts[t] = acc1;
    __syncthreads();
    if (t < 128) h1s[t] = fmaxf(parts[t] + parts[t + 128] + fcb1[t], 0.f);
    __syncthreads();

    // ---- fc2: 128 -> 64 (no act). stage [64][128] pad130; o = t&63, quarter = t>>6 ----
    for (int i = t; i < 2048; i += 256) {
        int row = i >> 5, fc = i & 31;
        float4 w4 = ((const float4*)fcw2)[row * 32 + fc];
        float* d = wst + row * 130 + (fc << 2);
        d[0] = w4.x; d[1] = w4.y; d[2] = w4.z; d[3] = w4.w;
    }
    __syncthreads();
    {
        int o2 = t & 63, kq = (t >> 6) << 5;
        const float* wr = wst + o2 * 130 + kq;
        const float* hr = h1s + kq;
        float a0 = 0.f, a1 = 0.f, a2 = 0.f, a3 = 0.f;
        #pragma unroll
        for (int k = 0; k < 32; k += 4) {
            a0 = fmaf(wr[k], hr[k], a0);
            a1 = fmaf(wr[k + 1], hr[k + 1], a1);
            a2 = fmaf(wr[k + 2], hr[k + 2], a2);
            a3 = fmaf(wr[k + 3], hr[k + 3], a3);
        }
        __syncthreads();
        parts[t] = (a0 + a1) + (a2 + a3);
    }
    __syncthreads();
    if (t < 64)
        gvs[t] = parts[t] + parts[t + 64] + parts[t + 128] + parts[t + 192] + fcb2[t];
    __syncthreads();

    // ---- fusion (fus overlays wst; fc2 reads done) ----
    #pragma unroll
    for (int i = 0; i < 4; i++) {
        int idx = t + (i << 8);
        int c = idx >> 4, p = idx & 15;
        fus[idx] = fmaxf(loc[(((size_t)b * 64 + c) * 16 + r) * 16 + p] + gvs[c], 0.f);
    }
    __syncthreads();
    // ---- bg 1x1: thread -> pixel p=t&15, co = (t>>4) + 16j ----
    {
        int p = t & 15, cg = t >> 4;
        float acc6[6];
        #pragma unroll
        for (int j = 0; j < 6; j++) acc6[j] = bgb[cg + (j << 4)];
        #pragma unroll 8
        for (int k = 0; k < 64; k++) {
            float f = fus[k * 16 + p];
            #pragma unroll
            for (int j = 0; j < 6; j++)
                acc6[j] += bgws[(cg + (j << 4)) * 65 + k] * f;
        }
        #pragma unroll
        for (int j = 0; j < 6; j++) {
            int co = cg + (j << 4);
            int c12 = co >> 3, d = co & 7;
            grid_r[(((((size_t)b * 8 + d) * 16 + r) * 16 + p) * 12) + c12] = acc6[j];
        }
    }
}

// ------- fused guide + slice + apply: one image row per block, 4 px/thread -------
__global__ void guide_slice(const float* __restrict__ fr, const float* __restrict__ grid_r,
                            const float* __restrict__ guw0, const float* __restrict__ gub0,
                            const float* __restrict__ guw1, const float* __restrict__ gub1,
                            float* __restrict__ gd_out, float* __restrict__ fin_out)
{
    __shared__ float gy[8 * 196];        // z-stride 196 (4 mod 32): conflict-free z
    int y = blockIdx.x, b = blockIdx.y;
    int t = threadIdx.x;

    float ys = (y + 0.5f) * 0.015625f - 0.5f;
    float fy = floorf(ys);
    int y0 = min(max((int)fy, 0), 15), y1 = min(y0 + 1, 15);
    float wy = ys - fy;

    const float* gb = grid_r + (size_t)b * 24576;
    for (int i = t; i < 1536; i += 256) {
        int z = i / 192, rem = i - z * 192;
        float a = gb[z * 3072 + y0 * 192 + rem];
        float c = gb[z * 3072 + y1 * 192 + rem];
        gy[z * 196 + rem] = a + wy * (c - a);
    }
    __syncthreads();

    int rowoff = (y << 10) + (t << 2);
    const float* frb = fr + (size_t)b * 3 * HW_;
    float4 R4 = *(const float4*)(frb + rowoff);
    float4 G4 = *(const float4*)(frb + HW_ + rowoff);
    float4 B4 = *(const float4*)(frb + 2 * HW_ + rowoff);
    float rr[4] = {R4.x, R4.y, R4.z, R4.w};
    float gg[4] = {G4.x, G4.y, G4.z, G4.w};
    float bb[4] = {B4.x, B4.y, B4.z, B4.w};
    float gdv[4], O0[4], O1[4], O2[4];

    #pragma unroll
    for (int j = 0; j < 4; j++) {
        float r = rr[j], g = gg[j], bl = bb[j];
        float s = gub1[0];
        #pragma unroll
        for (int c = 0; c < 16; c++) {
            float h = fmaf(guw0[c * 3], r, fmaf(guw0[c * 3 + 1], g,
                      fmaf(guw0[c * 3 + 2], bl, gub0[c])));
            s = fmaf(guw1[c], fmaxf(h, 0.f), s);
        }
        float gd = 1.f / (1.f + __expf(-s));
        gdv[j] = gd;

        int x = (t << 2) + j;
        float xs = (x + 0.5f) * 0.015625f - 0.5f;
        float fx = floorf(xs);
        int x0 = min(max((int)fx, 0), 15), x1 = min(x0 + 1, 15);
        float wx = xs - fx;
        float gz = gd * 8.f - 0.5f;
        float fz = floorf(gz);
        int z0 = min(max((int)fz, 0), 7), z1 = min(z0 + 1, 7);
        float wz = gz - fz;

        float acc[12];
        #pragma unroll
        for (int c = 0; c < 12; c++) acc[c] = 0.f;
        #pragma unroll
        for (int zi = 0; zi < 2; zi++) {
            int z = zi ? z1 : z0;
            float wzf = zi ? wz : 1.f - wz;
            const float4* p0 = (const float4*)(gy + z * 196 + x0 * 12);
            const float4* p1 = (const float4*)(gy + z * 196 + x1 * 12);
            float w0 = wzf * (1.f - wx), w1 = wzf * wx;
            #pragma unroll
            for (int q = 0; q < 3; q++) {
                float4 a = p0[q], c4 = p1[q];
                acc[q * 4 + 0] += w0 * a.x + w1 * c4.x;
                acc[q * 4 + 1] += w0 * a.y + w1 * c4.y;
                acc[q * 4 + 2] += w0 * a.z + w1 * c4.z;
                acc[q * 4 + 3] += w0 * a.w + w1 * c4.w;
            }
        }
        O0[j] = fmaf(acc[0], r, fmaf(acc[1], g, fmaf(acc[2], bl, acc[3])));
        O1[j] = fmaf(acc[4], r, fmaf(acc[5], g, fmaf(acc[6], bl, acc[7])));
        O2[j] = fmaf(acc[8], r, fmaf(acc[9], g, fmaf(acc[10], bl, acc[11])));
    }

    *(float4*)(gd_out + (size_t)b * HW_ + rowoff) = make_float4(gdv[0], gdv[1], gdv[2], gdv[3]);
    float* fb = fin_out + (size_t)b * 3 * HW_;
    *(float4*)(fb + rowoff)           = make_float4(O0[0], O0[1], O0[2], O0[3]);
    *(float4*)(fb + HW_ + rowoff)     = make_float4(O1[0], O1[1], O1[2], O1[3]);
    *(float4*)(fb + 2 * HW_ + rowoff) = make_float4(O2[0], O2[1], O2[2], O2[3]);
}

extern "C" void kernel_launch(void* const* d_in, const int* in_sizes, int n_in,
                              void* d_out, int out_size, void* d_ws, size_t ws_size,
                              hipStream_t stream) {
    const float* lr   = (const float*)d_in[0];
    const float* fr   = (const float*)d_in[1];
    const float* sw0  = (const float*)d_in[2];  const float* sb0 = (const float*)d_in[3];
    const float* sw1  = (const float*)d_in[4];  const float* sb1 = (const float*)d_in[5];
    const float* sw2  = (const float*)d_in[6];  const float* sb2 = (const float*)d_in[7];
    const float* sw3  = (const float*)d_in[8];  const float* sb3 = (const float*)d_in[9];
    const float* lw0  = (const float*)d_in[10]; const float* lb0 = (const float*)d_in[11];
    const float* lw1  = (const float*)d_in[12]; const float* lb1 = (const float*)d_in[13];
    const float* gcw0 = (const float*)d_in[14]; const float* gcb0 = (const float*)d_in[15];
    const float* gcw1 = (const float*)d_in[16]; const float* gcb1 = (const float*)d_in[17];
    const float* fcw0 = (const float*)d_in[18]; const float* fcb0 = (const float*)d_in[19];
    const float* fcw1 = (const float*)d_in[20]; const float* fcb1 = (const float*)d_in[21];
    const float* fcw2 = (const float*)d_in[22]; const float* fcb2 = (const float*)d_in[23];
    const float* bgw  = (const float*)d_in[24]; const float* bgb = (const float*)d_in[25];
    const float* guw0 = (const float*)d_in[26]; const float* gub0 = (const float*)d_in[27];
    const float* guw1 = (const float*)d_in[28]; const float* gub1 = (const float*)d_in[29];

    float* ws = (float*)d_ws;
    float* ws3    = ws;            // [2,64,16,16]   32768
    float* loc0   = ws + 32768;    // [2,64,16,16]   32768
    float* loc    = ws + 65536;    // [2,64,16,16]   32768
    float* g0     = ws + 98304;    // [2,64,8,8]     8192
    float* v      = ws + 106496;   // [2,1024]       2048
    float* h0     = ws + 108544;   // [2,256]        512
    float* grid_r = ws + 109056;   // [2,8,16,16,12] 49152

    float* gd_out  = (float*)d_out;             // [2,1024,1024]
    float* fin_out = (float*)d_out + 2 * HW_;   // [2,3,1024,1024]

    const int B = 2;

    k_splat<<<dim3(256, B), 256, 0, stream>>>(lr, sw0, sb0, sw1, sb1,
                                              sw2, sb2, sw3, sb3, ws3);
    k_loc0_gc0<<<dim3(80, B), 256, 0, stream>>>(ws3, lw0, lb0, loc0, gcw0, gcb0, g0);
    k_loc1_gc1<<<dim3(68, B), 256, 0, stream>>>(loc0, lw1, lb1, loc, g0, gcw1, gcb1, v);
    k_fc0<<<dim3(128), 256, 0, stream>>>(v, fcw0, fcb0, h0);
    k_fc12bg<<<dim3(16, B), 256, 0, stream>>>(h0, fcw1, fcb1, fcw2, fcb2,
                                              loc, bgw, bgb, grid_r);
    guide_slice<<<dim3(1024, B), 256, 0, stream>>>(
        fr, grid_r, guw0, gub0, guw1, gub1, gd_out, fin_out);
}